// Round 8
// baseline (111.249 us; speedup 1.0000x reference)
//
#include <hip/hip_runtime.h>

#define B_   32
#define IN_  784
#define HID_ 256
#define OUT_ 128
#define MH_  32
#define RATE_ 1e-3f

// workspace layout (float offsets)
#define OFF_OUT1  0       // [32][256]  vj1 init by kA2, accumulated by K1
#define OFF_VJ1T  8192    // [256][32]  vj1 transposed

// wave-wide dot product: NQ full rounds of 64 float4 + TAIL float4
template<int NQ, int TAIL>
__device__ __forceinline__ float waveDot(const float4* __restrict__ a,
                                         const float4* __restrict__ c, int lane) {
    float acc = 0.f;
    #pragma unroll
    for (int k = 0; k < NQ; ++k) {
        float4 xa = a[lane + 64 * k], wa = c[lane + 64 * k];
        acc = fmaf(xa.x, wa.x, acc); acc = fmaf(xa.y, wa.y, acc);
        acc = fmaf(xa.z, wa.z, acc); acc = fmaf(xa.w, wa.w, acc);
    }
    if (TAIL > 0 && lane < TAIL) {
        float4 xa = a[NQ * 64 + lane], wa = c[NQ * 64 + lane];
        acc = fmaf(xa.x, wa.x, acc); acc = fmaf(xa.y, wa.y, acc);
        acc = fmaf(xa.z, wa.z, acc); acc = fmaf(xa.w, wa.w, acc);
    }
    #pragma unroll
    for (int m = 1; m < 64; m <<= 1) acc += __shfl_xor(acc, m, 64);
    return acc;
}

// ---------------- kA2: vj1 = relu(x @ W1^T + b1) -> out1 (init), vjT1
__global__ void kA2(const float* __restrict__ x, const float* __restrict__ W1,
                    const float* __restrict__ b1, float* __restrict__ ws) {
    float* out1 = ws + OFF_OUT1;
    float* vjT1 = ws + OFF_VJ1T;
    int t = threadIdx.x, lane = t & 63;
    int p = blockIdx.x * 4 + (t >> 6);   // pair < 8192
    int b = p >> 8, o = p & 255;
    float acc = waveDot<3, 4>((const float4*)(x + b * IN_),
                              (const float4*)(W1 + o * IN_), lane);
    if (lane == 0) {
        float v = fmaxf(acc + b1[o], 0.f);
        out1[p] = v;
        vjT1[o * 32 + b] = v;
    }
}

// ---------------- K1: layer-1 meta ----------------
// t = b + 32*g; half-wave owns CPT contiguous i's. vi read DIRECTLY from
// x[b][i0..i0+CPT) (contiguous per thread, float2). h-chunks of 8 outer,
// params via LDS broadcast, cvm = c*vj+mb1 hoisted. Inner = 4 VALU/eval.
template<int IN_DIM, int OUT_DIM, int NCH, int CPT>
__global__ __launch_bounds__(256)
void layer_meta(const float* __restrict__ viRow,  // [B][IN_DIM] row-major acts
                const float* __restrict__ W,      // [OUT_DIM][IN_DIM]
                const float* __restrict__ vjT,    // [OUT_DIM][32]
                const float* __restrict__ mW1, const float* __restrict__ mb1,
                const float* __restrict__ mW2, const float* __restrict__ mb2,
                const int*   __restrict__ batch_num,
                float* __restrict__ Wnew,         // [OUT_DIM][IN_DIM]
                float* __restrict__ outAcc)       // [32][OUT_DIM]
{
    __shared__ float4 m4s[MH_];
    __shared__ float  w2s[MH_];
    __shared__ float  osh[4][32];

    int t = threadIdx.x;
    int b = t & 31, g = t >> 5;
    int o  = blockIdx.x / NCH;
    int i0 = (blockIdx.x % NCH) * (8 * CPT) + g * CPT;

    if (t < MH_) {
        m4s[t] = make_float4(mW1[t*3+0], mW1[t*3+1], mW1[t*3+2], mb1[t]);
        w2s[t] = mW2[t];
    }
    __syncthreads();

    float vjv = vjT[o * 32 + b];

    float vi[CPT], wv[CPT], s[CPT];
    {
        const float* xr = viRow + b * IN_DIM + i0;   // contiguous per thread
        const float* wr = W     + o * IN_DIM + i0;   // broadcast per half-wave
        #pragma unroll
        for (int k = 0; k < CPT / 2; ++k) {
            float2 v2 = *(const float2*)(xr + 2 * k);
            float2 w2v = *(const float2*)(wr + 2 * k);
            vi[2*k] = v2.x; vi[2*k+1] = v2.y;
            wv[2*k] = w2v.x; wv[2*k+1] = w2v.y;
        }
        #pragma unroll
        for (int k = 0; k < CPT; ++k) s[k] = 0.f;
    }

    #pragma unroll
    for (int hc = 0; hc < MH_ / 8; ++hc) {
        float a[8], bw[8], w2[8], cvm[8];
        #pragma unroll
        for (int j = 0; j < 8; ++j) {
            float4 m = m4s[hc * 8 + j];
            a[j]   = m.x;
            bw[j]  = m.y;
            cvm[j] = fmaf(m.z, vjv, m.w);
            w2[j]  = w2s[hc * 8 + j];
        }
        #pragma unroll
        for (int k = 0; k < CPT; ++k) {
            float vik = vi[k], wvk = wv[k];
            #pragma unroll
            for (int j = 0; j < 8; ++j) {
                float tt = fmaf(a[j], vik, fmaf(bw[j], wvk, cvm[j]));
                tt = fmaxf(tt, 0.f);
                s[k] = fmaf(w2[j], tt, s[k]);
            }
        }
    }

    float scale = RATE_ / (float)batch_num[0];
    float mb2v  = mb2[0];
    float outacc = 0.f;
    float r[CPT];
    #pragma unroll
    for (int k = 0; k < CPT; ++k) {
        float sh = (s[k] + mb2v) * scale;
        outacc = fmaf(vi[k], sh, outacc);
        r[k] = sh;
    }
    #pragma unroll
    for (int mm = 1; mm < 32; mm <<= 1) {
        #pragma unroll
        for (int k = 0; k < CPT; ++k) r[k] += __shfl_xor(r[k], mm);
    }
    if (b == 0) {
        #pragma unroll
        for (int k = 0; k < CPT; ++k)
            Wnew[o * IN_DIM + i0 + k] = wv[k] + r[k] * 0.03125f;
    }

    outacc += __shfl_xor(outacc, 32);
    if ((t & 32) == 0) osh[t >> 6][b] = outacc;
    __syncthreads();
    if (t < 32) {
        float v = osh[0][t] + osh[1][t] + osh[2][t] + osh[3][t];
        atomicAdd(&outAcc[t * OUT_DIM + o], v);
    }
}

// ---------------- K2: fused layer-2 (vj2 dots in-block + meta) ----------------
// 512 blocks: o = blk>>2, chunk = blk&3 (64 i each). 4 waves x 8 dots -> vjsh.
// Accumulates into out2 (pre-zeroed); chunk 0 also contributes vj2.
__global__ __launch_bounds__(256)
void layer2_fused(const float* __restrict__ out1,  // [32][256] complete
                  const float* __restrict__ W2,    // [128][256]
                  const float* __restrict__ b2,
                  const float* __restrict__ mW1, const float* __restrict__ mb1,
                  const float* __restrict__ mW2, const float* __restrict__ mb2,
                  const int*   __restrict__ batch_num,
                  float* __restrict__ W2n,         // [128][256]
                  float* __restrict__ out2)        // [32][128] pre-zeroed
{
    __shared__ float4 m4s[MH_];
    __shared__ float  w2s[MH_];
    __shared__ float  osh[4][32];
    __shared__ float  vjsh[32];

    int t = threadIdx.x;
    int lane = t & 63, wid = t >> 6;
    int o = blockIdx.x >> 2, chunk = blockIdx.x & 3;

    if (t < MH_) {
        m4s[t] = make_float4(mW1[t*3+0], mW1[t*3+1], mW1[t*3+2], mb1[t]);
        w2s[t] = mW2[t];
    }

    // vj2 dots: wave wid computes b = wid*8+q, q in [0,8)
    #pragma unroll
    for (int q = 0; q < 8; ++q) {
        int bv = wid * 8 + q;
        float acc = waveDot<1, 0>((const float4*)(out1 + bv * HID_),
                                  (const float4*)(W2 + o * HID_), lane);
        if (lane == 0) vjsh[bv] = fmaxf(acc + b2[o], 0.f);
    }
    __syncthreads();

    int b = t & 31, g = t >> 5;
    constexpr int CPT = 8;
    int i0 = chunk * 64 + g * CPT;

    float vjv = vjsh[b];
    float vi[CPT], wv[CPT], s[CPT];
    {
        const float* xr = out1 + b * HID_ + i0;
        const float* wr = W2   + o * HID_ + i0;
        #pragma unroll
        for (int k = 0; k < CPT / 2; ++k) {
            float2 v2 = *(const float2*)(xr + 2 * k);
            float2 w2v = *(const float2*)(wr + 2 * k);
            vi[2*k] = v2.x; vi[2*k+1] = v2.y;
            wv[2*k] = w2v.x; wv[2*k+1] = w2v.y;
        }
        #pragma unroll
        for (int k = 0; k < CPT; ++k) s[k] = 0.f;
    }

    #pragma unroll
    for (int hc = 0; hc < MH_ / 8; ++hc) {
        float a[8], bw[8], w2[8], cvm[8];
        #pragma unroll
        for (int j = 0; j < 8; ++j) {
            float4 m = m4s[hc * 8 + j];
            a[j]   = m.x;
            bw[j]  = m.y;
            cvm[j] = fmaf(m.z, vjv, m.w);
            w2[j]  = w2s[hc * 8 + j];
        }
        #pragma unroll
        for (int k = 0; k < CPT; ++k) {
            float vik = vi[k], wvk = wv[k];
            #pragma unroll
            for (int j = 0; j < 8; ++j) {
                float tt = fmaf(a[j], vik, fmaf(bw[j], wvk, cvm[j]));
                tt = fmaxf(tt, 0.f);
                s[k] = fmaf(w2[j], tt, s[k]);
            }
        }
    }

    float scale = RATE_ / (float)batch_num[0];
    float mb2v  = mb2[0];
    float outacc = 0.f;
    float r[CPT];
    #pragma unroll
    for (int k = 0; k < CPT; ++k) {
        float sh = (s[k] + mb2v) * scale;
        outacc = fmaf(vi[k], sh, outacc);
        r[k] = sh;
    }
    #pragma unroll
    for (int mm = 1; mm < 32; mm <<= 1) {
        #pragma unroll
        for (int k = 0; k < CPT; ++k) r[k] += __shfl_xor(r[k], mm);
    }
    if (b == 0) {
        #pragma unroll
        for (int k = 0; k < CPT; ++k)
            W2n[o * HID_ + i0 + k] = wv[k] + r[k] * 0.03125f;
    }

    outacc += __shfl_xor(outacc, 32);
    if ((t & 32) == 0) osh[t >> 6][b] = outacc;
    __syncthreads();
    if (t < 32) {
        float v = osh[0][t] + osh[1][t] + osh[2][t] + osh[3][t];
        if (chunk == 0) v += vjsh[t];           // vj2 contributed exactly once
        atomicAdd(&out2[t * OUT_ + o], v);
    }
}

extern "C" void kernel_launch(void* const* d_in, const int* in_sizes, int n_in,
                              void* d_out, int out_size, void* d_ws, size_t ws_size,
                              hipStream_t stream) {
    const float* x   = (const float*)d_in[0];
    const float* W1  = (const float*)d_in[1];
    const float* b1  = (const float*)d_in[2];
    const float* W2  = (const float*)d_in[3];
    const float* b2  = (const float*)d_in[4];
    const float* mW1 = (const float*)d_in[5];
    const float* mb1 = (const float*)d_in[6];
    const float* mW2 = (const float*)d_in[7];
    const float* mb2 = (const float*)d_in[8];
    const int* batch_num = (const int*)d_in[9];

    float* out2 = (float*)d_out;                // [32*128]
    float* W1n  = out2 + B_ * OUT_;             // [256*784]
    float* W2n  = W1n + HID_ * IN_;             // [128*256]
    float* ws   = (float*)d_ws;

    // zero the out2 accumulator region (harness poisons d_out with 0xAA)
    hipMemsetAsync(out2, 0, B_ * OUT_ * sizeof(float), stream);
    // vj1 -> out1 init + vjT1
    kA2<<<2048, 256, 0, stream>>>(x, W1, b1, ws);
    // layer-1 meta: 256 o * 7 chunks; vi direct from x
    layer_meta<IN_, HID_, 7, 14><<<HID_ * 7, 256, 0, stream>>>(
        x, W1, ws + OFF_VJ1T, mW1, mb1, mW2, mb2, batch_num,
        W1n, ws + OFF_OUT1);
    // layer-2 fused: 128 o * 4 chunks; vj2 recomputed in-block
    layer2_fused<<<OUT_ * 4, 256, 0, stream>>>(
        ws + OFF_OUT1, W2, b2, mW1, mb1, mW2, mb2, batch_num,
        W2n, out2);
}